// Round 3
// baseline (1014.845 us; speedup 1.0000x reference)
//
#include <hip/hip_runtime.h>
#include <math.h>

// FAVOR+ linear attention (Performer), fp32, MI355X.
// b=4 n=4096 h=8 d=64 m=256.
// Pipeline:
//   1 k_init    : ws zero/-inf init (atomic targets)
//   2 k_diag    : diag1/diag2 = 0.0625*sum(v^2) per position
//   3 k_proj<false>: dd2 = (v2)·(P*scale)^T -> stored raw in v2p out region; per-(b,h) max via atomicMaxF
//   4 k_proj<true> : v1p final = ratio*(exp(dd1 - diag1 - rowmax) + eps)  (fused per-position max)
//   5 k_v2accum : v2p = ratio*(exp(dd2 - diag2 - bhmax)+eps) in place; accumulate v2x[bh][m][d], v2_sum[bh][m]
//   6 k_pv      : out = (v1p @ v2x) / (v1p · v2_sum)

namespace {
constexpr int B_ = 4, N_ = 4096, H_ = 8, D_ = 64, M_ = 256;
constexpr int BH_ = B_ * H_;          // 32
constexpr int POS_ = B_ * N_ * H_;    // 131072
constexpr float SCALE_ = 0.35355339059327378f;  // 64^-0.25 (tau=1)
constexpr float RATIO_ = 0.0625f;               // 256^-0.5
constexpr float FEPS_ = 1e-6f;

// ws layout (float offsets)
constexpr int WS_BHMAX = 0;                       // 32 floats, init -inf
constexpr int WS_V2X   = 32;                      // 32*256*64 = 524288
constexpr int WS_V2SUM = WS_V2X + BH_ * M_ * D_;  // 524320, 8192 floats
constexpr int WS_DIAG1 = WS_V2SUM + BH_ * M_;     // 532512
constexpr int WS_DIAG2 = WS_DIAG1 + POS_;         // 663584
constexpr int WS_ZERO_END = WS_DIAG1;             // [32, WS_DIAG1) zeroed
}

__device__ __forceinline__ void atomicMaxF(float* addr, float v) {
  // ordered-int trick; works given init = -inf
  if (v >= 0.f)
    atomicMax((int*)addr, __float_as_int(v));
  else
    atomicMin((unsigned int*)addr, __float_as_uint(v));
}

// ---------------------------------------------------------------- init
__global__ void k_init(float* __restrict__ ws) {
  int i = blockIdx.x * 256 + threadIdx.x;
  int stride = gridDim.x * 256;
  for (; i < WS_ZERO_END; i += stride) {
    ws[i] = (i < 32) ? -INFINITY : 0.f;
  }
}

// ---------------------------------------------------------------- diag
// 64 rows per block, 4 threads per row (16 floats each)
__global__ void k_diag(const float* __restrict__ v1, const float* __restrict__ v2,
                       float* __restrict__ ws) {
  int t = threadIdx.x;
  int r = t >> 2, seg = t & 3;
  int rowg = blockIdx.x * 64 + r;  // 0 .. 2*POS-1
  const float* src;
  float* dst;
  int row;
  if (rowg < POS_) { src = v1; dst = ws + WS_DIAG1; row = rowg; }
  else             { src = v2; dst = ws + WS_DIAG2; row = rowg - POS_; }
  const float4* p = reinterpret_cast<const float4*>(src + (size_t)row * 64) + seg * 4;
  float s = 0.f;
#pragma unroll
  for (int j = 0; j < 4; ++j) {
    float4 v = p[j];
    s = fmaf(v.x, v.x, s); s = fmaf(v.y, v.y, s);
    s = fmaf(v.z, v.z, s); s = fmaf(v.w, v.w, s);
  }
  s += __shfl_xor(s, 1);
  s += __shfl_xor(s, 2);
  if (seg == 0) dst[row] = 0.0625f * s;  // 0.5 * SCALE^2 * sum
}

// ---------------------------------------------------------------- projection
// 256 threads; thread t owns feature m=t (P row pre-scaled in 64 VGPRs).
// Block handles 128 consecutive n of one (b,h). IS_QUERY: fused rowmax+exp -> final v1p.
// else: store raw dd; block-reduce max -> atomicMaxF per bh.
template <bool IS_QUERY>
__global__ __launch_bounds__(256) void k_proj(const float* __restrict__ vec,
                                              const float* __restrict__ Pm,
                                              float* __restrict__ ddout,
                                              float* __restrict__ ws) {
  int t = threadIdx.x;
  int bh = blockIdx.x >> 5;       // 32 tiles per bh
  int tile = blockIdx.x & 31;
  int b = bh >> 3, h = bh & 7;

  float4 pr[16];
  {
    const float4* pp = reinterpret_cast<const float4*>(Pm + t * 64);
#pragma unroll
    for (int j = 0; j < 16; ++j) {
      float4 v = pp[j];
      pr[j].x = v.x * SCALE_; pr[j].y = v.y * SCALE_;
      pr[j].z = v.z * SCALE_; pr[j].w = v.w * SCALE_;
    }
  }

  __shared__ float wmax[2][4][8];
  __shared__ float wm[4];
  int wv = t >> 6, ln = t & 63;
  float vmax = -INFINITY;
  const float* diag1 = ws + WS_DIAG1;

  int nbase = tile * 128;
  for (int chunk = 0; chunk < 16; ++chunk) {
    float a[8];
#pragma unroll
    for (int cp = 0; cp < 8; ++cp) {
      int n = nbase + chunk * 8 + cp;
      int pg = (b * N_ + n) * H_ + h;
      const float4* r4 = reinterpret_cast<const float4*>(vec + (size_t)pg * 64);
      float acc = 0.f;
#pragma unroll
      for (int j = 0; j < 16; ++j) {
        float4 dv = r4[j];
        acc = fmaf(dv.x, pr[j].x, acc);
        acc = fmaf(dv.y, pr[j].y, acc);
        acc = fmaf(dv.z, pr[j].z, acc);
        acc = fmaf(dv.w, pr[j].w, acc);
      }
      a[cp] = acc;
    }
    if (IS_QUERY) {
      int buf = chunk & 1;
#pragma unroll
      for (int cp = 0; cp < 8; ++cp) {
        float m = a[cp];
#pragma unroll
        for (int o = 1; o < 64; o <<= 1) m = fmaxf(m, __shfl_xor(m, o));
        if (ln == 0) wmax[buf][wv][cp] = m;
      }
      __syncthreads();
#pragma unroll
      for (int cp = 0; cp < 8; ++cp) {
        int n = nbase + chunk * 8 + cp;
        int pg = (b * N_ + n) * H_ + h;
        float mx = fmaxf(fmaxf(wmax[buf][0][cp], wmax[buf][1][cp]),
                         fmaxf(wmax[buf][2][cp], wmax[buf][3][cp]));
        float dgv = diag1[pg];
        float val = RATIO_ * (__expf(a[cp] - dgv - mx) + FEPS_);
        ddout[pg * M_ + t] = val;
      }
    } else {
#pragma unroll
      for (int cp = 0; cp < 8; ++cp) {
        vmax = fmaxf(vmax, a[cp]);
        int n = nbase + chunk * 8 + cp;
        int pg = (b * N_ + n) * H_ + h;
        ddout[pg * M_ + t] = a[cp];
      }
    }
  }
  if (!IS_QUERY) {
#pragma unroll
    for (int o = 1; o < 64; o <<= 1) vmax = fmaxf(vmax, __shfl_xor(vmax, o));
    if (ln == 0) wm[wv] = vmax;
    __syncthreads();
    if (t == 0) {
      float m = fmaxf(fmaxf(wm[0], wm[1]), fmaxf(wm[2], wm[3]));
      atomicMaxF(ws + WS_BHMAX + bh, m);
    }
  }
}

// ---------------------------------------------------------------- v2 exp + accumulate
// grid 512 = bh*16 + chunk(256 n). 8 stage iters x 32 n.
// thread: mg=t&31 owns m0=mg*8 ; dgi=t>>5 owns d0=dgi*8 ; acc[8][8].
__global__ __launch_bounds__(256) void k_v2accum(const float* __restrict__ x,
                                                 float* __restrict__ v2p,  // in: dd2, out: v2p
                                                 float* __restrict__ ws) {
  __shared__ float sP[32][264];
  __shared__ float sX[32][64];
  int t = threadIdx.x;
  int bh = blockIdx.x >> 4, chunk = blockIdx.x & 15;
  int b = bh >> 3, h = bh & 7;
  int n0 = chunk * 256;
  float bhmax = ws[WS_BHMAX + bh];
  const float* diag2 = ws + WS_DIAG2;

  int mg = t & 31, dgi = t >> 5;
  int pl8 = t >> 3, seg = t & 7;

  float acc[8][8];
  float acc2[8];
#pragma unroll
  for (int i = 0; i < 8; ++i) {
    acc2[i] = 0.f;
#pragma unroll
    for (int j = 0; j < 8; ++j) acc[i][j] = 0.f;
  }

  for (int it = 0; it < 8; ++it) {
    __syncthreads();
    {
      int n = n0 + it * 32 + pl8;
      int pg = (b * N_ + n) * H_ + h;
      float dgv = diag2[pg];
      float* gp = v2p + (size_t)pg * M_;
#pragma unroll
      for (int j = 0; j < 8; ++j) {
        int m = seg * 4 + j * 32;
        float4 dv = *reinterpret_cast<const float4*>(gp + m);
        float4 vv;
        vv.x = RATIO_ * (__expf(dv.x - dgv - bhmax) + FEPS_);
        vv.y = RATIO_ * (__expf(dv.y - dgv - bhmax) + FEPS_);
        vv.z = RATIO_ * (__expf(dv.z - dgv - bhmax) + FEPS_);
        vv.w = RATIO_ * (__expf(dv.w - dgv - bhmax) + FEPS_);
        *reinterpret_cast<float4*>(gp + m) = vv;
        *reinterpret_cast<float4*>(&sP[pl8][m]) = vv;
      }
      const float* gx = x + (size_t)pg * 64;
#pragma unroll
      for (int j = 0; j < 2; ++j) {
        int f = seg * 2 + j;
        float4 xv = *reinterpret_cast<const float4*>(gx + f * 4);
        *reinterpret_cast<float4*>(&sX[pl8][f * 4]) = xv;
      }
    }
    __syncthreads();
#pragma unroll 4
    for (int nn = 0; nn < 32; ++nn) {
      float4 a0 = *reinterpret_cast<const float4*>(&sP[nn][mg * 8]);
      float4 a1 = *reinterpret_cast<const float4*>(&sP[nn][mg * 8 + 4]);
      float4 b0 = *reinterpret_cast<const float4*>(&sX[nn][dgi * 8]);
      float4 b1 = *reinterpret_cast<const float4*>(&sX[nn][dgi * 8 + 4]);
      float av[8] = {a0.x, a0.y, a0.z, a0.w, a1.x, a1.y, a1.z, a1.w};
      float bv[8] = {b0.x, b0.y, b0.z, b0.w, b1.x, b1.y, b1.z, b1.w};
#pragma unroll
      for (int i = 0; i < 8; ++i) {
        acc2[i] += av[i];
#pragma unroll
        for (int j = 0; j < 8; ++j) acc[i][j] = fmaf(av[i], bv[j], acc[i][j]);
      }
    }
  }

  float* vx = ws + WS_V2X + bh * M_ * D_;
#pragma unroll
  for (int i = 0; i < 8; ++i)
#pragma unroll
    for (int j = 0; j < 8; ++j)
      atomicAdd(vx + (mg * 8 + i) * 64 + dgi * 8 + j, acc[i][j]);
  if (dgi == 0) {
    float* vs = ws + WS_V2SUM + bh * M_;
#pragma unroll
    for (int i = 0; i < 8; ++i) atomicAdd(vs + mg * 8 + i, acc2[i]);
  }
}

// ---------------------------------------------------------------- PV + out
// grid 2048 = bh*64 + tile(64 pos). thread (pg_=t&15, dg=t>>4) owns 4 pos x 4 d.
// Two m-halves of 128 to fit LDS (sA 33KB + sB 34.8KB -> 2 blocks/CU).
__global__ __launch_bounds__(256) void k_pv(const float* __restrict__ v1p,
                                            float* __restrict__ ws,
                                            float* __restrict__ out) {
  __shared__ float sA[64][129];   // v1p tile (pad 129 -> 2-way free reads)
  __shared__ float sB[128][68];   // v2x half (pad 68)
  __shared__ float sVs[256];
  int t = threadIdx.x;
  int bh = blockIdx.x >> 6, tile = blockIdx.x & 63;
  int b = bh >> 3, h = bh & 7;
  int n0 = tile * 64;
  int pg_ = t & 15, dg = t >> 4;
  int pl = t >> 2, sseg = t & 3;
  int mr = t >> 1, hseg = t & 1;

  if (t < 64) {
    float4 v = *reinterpret_cast<const float4*>(ws + WS_V2SUM + bh * M_ + t * 4);
    *reinterpret_cast<float4*>(&sVs[t * 4]) = v;
  }

  float acc1[4][4];
  float acc2[4];
#pragma unroll
  for (int i = 0; i < 4; ++i) {
    acc2[i] = 0.f;
#pragma unroll
    for (int j = 0; j < 4; ++j) acc1[i][j] = 0.f;
  }

  int posg_base = (b * N_ + n0) * H_ + h;

  for (int half = 0; half < 2; ++half) {
    __syncthreads();
    int m0 = half * 128;
    {
      int pg = posg_base + pl * H_;
      const float* gp = v1p + (size_t)pg * M_ + m0;
#pragma unroll
      for (int j = 0; j < 8; ++j) {
        int m = sseg * 4 + j * 16;
        float4 v = *reinterpret_cast<const float4*>(gp + m);
        sA[pl][m] = v.x; sA[pl][m + 1] = v.y;
        sA[pl][m + 2] = v.z; sA[pl][m + 3] = v.w;
      }
      const float* gb = ws + WS_V2X + bh * M_ * D_ + (m0 + mr) * 64 + hseg * 32;
#pragma unroll
      for (int j = 0; j < 8; ++j) {
        float4 v = *reinterpret_cast<const float4*>(gb + j * 4);
        *reinterpret_cast<float4*>(&sB[mr][hseg * 32 + j * 4]) = v;
      }
    }
    __syncthreads();
#pragma unroll 4
    for (int m = 0; m < 128; ++m) {
      float a0 = sA[4 * pg_ + 0][m];
      float a1 = sA[4 * pg_ + 1][m];
      float a2 = sA[4 * pg_ + 2][m];
      float a3 = sA[4 * pg_ + 3][m];
      float4 bv = *reinterpret_cast<const float4*>(&sB[m][dg * 4]);
      float vsm = sVs[m0 + m];
      acc1[0][0] = fmaf(a0, bv.x, acc1[0][0]); acc1[0][1] = fmaf(a0, bv.y, acc1[0][1]);
      acc1[0][2] = fmaf(a0, bv.z, acc1[0][2]); acc1[0][3] = fmaf(a0, bv.w, acc1[0][3]);
      acc1[1][0] = fmaf(a1, bv.x, acc1[1][0]); acc1[1][1] = fmaf(a1, bv.y, acc1[1][1]);
      acc1[1][2] = fmaf(a1, bv.z, acc1[1][2]); acc1[1][3] = fmaf(a1, bv.w, acc1[1][3]);
      acc1[2][0] = fmaf(a2, bv.x, acc1[2][0]); acc1[2][1] = fmaf(a2, bv.y, acc1[2][1]);
      acc1[2][2] = fmaf(a2, bv.z, acc1[2][2]); acc1[2][3] = fmaf(a2, bv.w, acc1[2][3]);
      acc1[3][0] = fmaf(a3, bv.x, acc1[3][0]); acc1[3][1] = fmaf(a3, bv.y, acc1[3][1]);
      acc1[3][2] = fmaf(a3, bv.z, acc1[3][2]); acc1[3][3] = fmaf(a3, bv.w, acc1[3][3]);
      acc2[0] = fmaf(a0, vsm, acc2[0]);
      acc2[1] = fmaf(a1, vsm, acc2[1]);
      acc2[2] = fmaf(a2, vsm, acc2[2]);
      acc2[3] = fmaf(a3, vsm, acc2[3]);
    }
  }

#pragma unroll
  for (int i = 0; i < 4; ++i) {
    int pg = posg_base + (4 * pg_ + i) * H_;
    float inv = 1.f / acc2[i];
    float4 o;
    o.x = acc1[i][0] * inv; o.y = acc1[i][1] * inv;
    o.z = acc1[i][2] * inv; o.w = acc1[i][3] * inv;
    *reinterpret_cast<float4*>(out + (size_t)pg * 64 + dg * 4) = o;
  }
}

// ---------------------------------------------------------------- launch
extern "C" void kernel_launch(void* const* d_in, const int* in_sizes, int n_in,
                              void* d_out, int out_size, void* d_ws, size_t ws_size,
                              hipStream_t stream) {
  const float* x  = (const float*)d_in[0];
  const float* v1 = (const float*)d_in[1];
  const float* v2 = (const float*)d_in[2];
  const float* Pm = (const float*)d_in[3];
  float* out = (float*)d_out;
  float* v1p = out + (size_t)POS_ * D_;           // 8388608
  float* v2p = v1p + (size_t)POS_ * M_;           // 41943040
  float* ws = (float*)d_ws;

  k_init<<<1024, 256, 0, stream>>>(ws);
  k_diag<<<2 * POS_ / 64, 256, 0, stream>>>(v1, v2, ws);
  k_proj<false><<<BH_ * 32, 256, 0, stream>>>(v2, Pm, v2p, ws);  // raw dd2 + bh max
  k_proj<true><<<BH_ * 32, 256, 0, stream>>>(v1, Pm, v1p, ws);   // final v1p
  k_v2accum<<<BH_ * 16, 256, 0, stream>>>(x, v2p, ws);           // v2p + v2x/v2_sum
  k_pv<<<BH_ * 64, 256, 0, stream>>>(v1p, ws, out);              // out
}